// Round 1
// baseline (4327.309 us; speedup 1.0000x reference)
//
#include <hip/hip_runtime.h>

// GCN: 3 x (GCNConv -> BN(train) -> PReLU), N=100000, E=1600000, 128->64->64->64
// Strategy: dinv via atomic degree count; per layer: GEMM (writes hs=h*dinv and
// agg=hs as self-loop init), edge scatter with float atomics, BN reduce + apply.

constexpr float BN_EPS = 1e-5f;

__global__ void count_deg(const int* __restrict__ dst, float* __restrict__ deg, int E) {
    int e = blockIdx.x * blockDim.x + threadIdx.x;
    if (e < E) atomicAdd(&deg[dst[e]], 1.0f);
}

__global__ void finalize_dinv(float* __restrict__ deg, int N) {
    int i = blockIdx.x * blockDim.x + threadIdx.x;
    if (i < N) deg[i] = rsqrtf(deg[i] + 1.0f);  // +1 self-loop; deg>=1 always
}

// C[row][c] = (X[row][:] @ W[:][c]) * dinv[row]; written to both hs and agg.
// Block: 256 threads, 64 rows x 64 cols per block, 4x4 register tile/thread.
template <int K>
__global__ __launch_bounds__(256) void gemm_scale(
    const float* __restrict__ X, const float* __restrict__ W,
    const float* __restrict__ dinv, float* __restrict__ hs,
    float* __restrict__ agg, int N) {
    static_assert(K % 64 == 0, "K must be multiple of 64");
    __shared__ float Ws[K * 64];     // W staged whole (<=32 KB)
    __shared__ float Xs[64 * 65];    // 64 rows x 64 k-chunk, stride 65 (pad)

    const int t = threadIdx.x;
    const int rowBase = blockIdx.x * 64;

    // stage W: K*16 float4s
    for (int q = t; q < K * 16; q += 256)
        ((float4*)Ws)[q] = ((const float4*)W)[q];

    const int tx = t & 15;   // col group: cols 4*tx..4*tx+3
    const int ty = t >> 4;   // row group: rows 4*ty..4*ty+3

    float acc[4][4];
#pragma unroll
    for (int i = 0; i < 4; ++i)
#pragma unroll
        for (int j = 0; j < 4; ++j) acc[i][j] = 0.f;

#pragma unroll
    for (int kh = 0; kh < K / 64; ++kh) {
        __syncthreads();  // also fences Ws on first pass
        // stage X chunk: 64 rows x 16 float4, coalesced (16 lanes per row)
#pragma unroll
        for (int j = 0; j < 4; ++j) {
            int q = t + j * 256;
            int r = q >> 4, kk = q & 15;
            int row = rowBase + r;
            float4 v = make_float4(0.f, 0.f, 0.f, 0.f);
            if (row < N)
                v = *(const float4*)(X + (size_t)row * K + kh * 64 + kk * 4);
            float* p = &Xs[r * 65 + kk * 4];
            p[0] = v.x; p[1] = v.y; p[2] = v.z; p[3] = v.w;
        }
        __syncthreads();
#pragma unroll 8
        for (int k = 0; k < 64; ++k) {
            float4 w4 = *(const float4*)&Ws[(kh * 64 + k) * 64 + tx * 4];
#pragma unroll
            for (int i = 0; i < 4; ++i) {
                float xv = Xs[(ty * 4 + i) * 65 + k];
                acc[i][0] = fmaf(xv, w4.x, acc[i][0]);
                acc[i][1] = fmaf(xv, w4.y, acc[i][1]);
                acc[i][2] = fmaf(xv, w4.z, acc[i][2]);
                acc[i][3] = fmaf(xv, w4.w, acc[i][3]);
            }
        }
    }

#pragma unroll
    for (int i = 0; i < 4; ++i) {
        int row = rowBase + ty * 4 + i;
        if (row < N) {
            float dv = dinv[row];
            float4 o = make_float4(acc[i][0] * dv, acc[i][1] * dv,
                                   acc[i][2] * dv, acc[i][3] * dv);
            *(float4*)(hs + (size_t)row * 64 + tx * 4) = o;
            *(float4*)(agg + (size_t)row * 64 + tx * 4) = o;
        }
    }
}

// agg[dst] += hs[src]  (per edge; 16 lanes/edge, float4 gather + 4 atomics)
__global__ __launch_bounds__(256) void scatter_edges(
    const int* __restrict__ src, const int* __restrict__ dst,
    const float4* __restrict__ hs4, float* __restrict__ agg, int E) {
    int tid = blockIdx.x * blockDim.x + threadIdx.x;
    int lane = tid & 15;
    int e = tid >> 4;
    if (e >= E) return;
    int s = src[e], d = dst[e];
    float4 v = hs4[(size_t)s * 16 + lane];
    float* p = agg + (size_t)d * 64 + lane * 4;
    atomicAdd(p + 0, v.x);
    atomicAdd(p + 1, v.y);
    atomicAdd(p + 2, v.z);
    atomicAdd(p + 3, v.w);
}

// per-feature sum / sumsq of y = dinv[row]*agg[row][c] + b[c]
__global__ __launch_bounds__(256) void bn_reduce(
    const float* __restrict__ agg, const float* __restrict__ dinv,
    const float* __restrict__ b, float* __restrict__ stats, int N) {
    const int t = threadIdx.x;
    const int col = t & 63, rg = t >> 6;
    float s = 0.f, sq = 0.f;
    const float bc = b[col];
    for (int row = blockIdx.x * 4 + rg; row < N; row += gridDim.x * 4) {
        float y = dinv[row] * agg[(size_t)row * 64 + col] + bc;
        s += y;
        sq = fmaf(y, y, sq);
    }
    __shared__ float ls[256], lq[256];
    ls[t] = s; lq[t] = sq;
    __syncthreads();
    if (t < 64) {
        s = ls[t] + ls[t + 64] + ls[t + 128] + ls[t + 192];
        sq = lq[t] + lq[t + 64] + lq[t + 128] + lq[t + 192];
        atomicAdd(&stats[t], s);
        atomicAdd(&stats[64 + t], sq);
    }
}

__global__ void bn_final(float* __restrict__ stats, const float* __restrict__ g,
                         const float* __restrict__ be, float invN) {
    int c = threadIdx.x;  // 64 threads
    float mu = stats[c] * invN;
    float var = stats[64 + c] * invN - mu * mu;
    float sc = g[c] * rsqrtf(var + BN_EPS);
    stats[128 + c] = sc;
    stats[192 + c] = be[c] - mu * sc;
}

// out = prelu( (dinv*agg + b)*scale + shift, a )
__global__ __launch_bounds__(256) void bn_apply(
    const float4* __restrict__ agg4, const float* __restrict__ dinv,
    const float* __restrict__ b, const float* __restrict__ stats,
    const float* __restrict__ a, float4* __restrict__ out4, int N) {
    int i = blockIdx.x * blockDim.x + threadIdx.x;  // over N*16 float4s
    if (i >= N * 16) return;
    int row = i >> 4;
    int cg = (i & 15) * 4;
    float dv = dinv[row];
    float4 v = agg4[i];
    float4 o;
    {
        float y = fmaf(dv, v.x, b[cg + 0]);
        float z = fmaf(y, stats[128 + cg + 0], stats[192 + cg + 0]);
        o.x = z >= 0.f ? z : a[cg + 0] * z;
    }
    {
        float y = fmaf(dv, v.y, b[cg + 1]);
        float z = fmaf(y, stats[128 + cg + 1], stats[192 + cg + 1]);
        o.y = z >= 0.f ? z : a[cg + 1] * z;
    }
    {
        float y = fmaf(dv, v.z, b[cg + 2]);
        float z = fmaf(y, stats[128 + cg + 2], stats[192 + cg + 2]);
        o.z = z >= 0.f ? z : a[cg + 2] * z;
    }
    {
        float y = fmaf(dv, v.w, b[cg + 3]);
        float z = fmaf(y, stats[128 + cg + 3], stats[192 + cg + 3]);
        o.w = z >= 0.f ? z : a[cg + 3] * z;
    }
    out4[i] = o;
}

extern "C" void kernel_launch(void* const* d_in, const int* in_sizes, int n_in,
                              void* d_out, int out_size, void* d_ws, size_t ws_size,
                              hipStream_t stream) {
    const float* x  = (const float*)d_in[0];
    const int*   ei = (const int*)d_in[1];
    const int N = in_sizes[0] / 128;
    const int E = in_sizes[1] / 2;
    const int* srcp = ei;
    const int* dstp = ei + E;

    const float* W1 = (const float*)d_in[2];
    const float* b1 = (const float*)d_in[3];
    const float* g1 = (const float*)d_in[4];
    const float* be1 = (const float*)d_in[5];
    const float* a1 = (const float*)d_in[6];
    const float* W2 = (const float*)d_in[7];
    const float* b2 = (const float*)d_in[8];
    const float* g2 = (const float*)d_in[9];
    const float* be2 = (const float*)d_in[10];
    const float* a2 = (const float*)d_in[11];
    const float* W3 = (const float*)d_in[12];
    const float* b3 = (const float*)d_in[13];
    const float* g3 = (const float*)d_in[14];
    const float* be3 = (const float*)d_in[15];
    const float* a3 = (const float*)d_in[16];

    // workspace layout (floats): dinv[N] | stats[256] | hs[N*64] | agg[N*64] | xcur[N*64]
    float* ws = (float*)d_ws;
    float* dinv  = ws;
    float* stats = ws + N;                      // N=100000 divisible by 4 -> aligned
    float* hs    = stats + 256;
    float* agg   = hs + (size_t)N * 64;
    float* xcur  = agg + (size_t)N * 64;

    hipMemsetAsync(dinv, 0, (size_t)N * sizeof(float), stream);
    count_deg<<<(E + 255) / 256, 256, 0, stream>>>(dstp, dinv, E);
    finalize_dinv<<<(N + 255) / 256, 256, 0, stream>>>(dinv, N);

    const int gemmGrid = (N + 63) / 64;
    const int scatGrid = (int)(((size_t)E * 16 + 255) / 256);
    const int applyGrid = (N * 16 + 255) / 256;
    const float invN = 1.0f / (float)N;

    // ---- layer 1 (K=128) ----
    gemm_scale<128><<<gemmGrid, 256, 0, stream>>>(x, W1, dinv, hs, agg, N);
    scatter_edges<<<scatGrid, 256, 0, stream>>>(srcp, dstp, (const float4*)hs, agg, E);
    hipMemsetAsync(stats, 0, 128 * sizeof(float), stream);
    bn_reduce<<<1024, 256, 0, stream>>>(agg, dinv, b1, stats, N);
    bn_final<<<1, 64, 0, stream>>>(stats, g1, be1, invN);
    bn_apply<<<applyGrid, 256, 0, stream>>>((const float4*)agg, dinv, b1, stats, a1,
                                            (float4*)xcur, N);

    // ---- layer 2 (K=64) ----
    gemm_scale<64><<<gemmGrid, 256, 0, stream>>>(xcur, W2, dinv, hs, agg, N);
    scatter_edges<<<scatGrid, 256, 0, stream>>>(srcp, dstp, (const float4*)hs, agg, E);
    hipMemsetAsync(stats, 0, 128 * sizeof(float), stream);
    bn_reduce<<<1024, 256, 0, stream>>>(agg, dinv, b2, stats, N);
    bn_final<<<1, 64, 0, stream>>>(stats, g2, be2, invN);
    bn_apply<<<applyGrid, 256, 0, stream>>>((const float4*)agg, dinv, b2, stats, a2,
                                            (float4*)xcur, N);

    // ---- layer 3 (K=64) ----
    gemm_scale<64><<<gemmGrid, 256, 0, stream>>>(xcur, W3, dinv, hs, agg, N);
    scatter_edges<<<scatGrid, 256, 0, stream>>>(srcp, dstp, (const float4*)hs, agg, E);
    hipMemsetAsync(stats, 0, 128 * sizeof(float), stream);
    bn_reduce<<<1024, 256, 0, stream>>>(agg, dinv, b3, stats, N);
    bn_final<<<1, 64, 0, stream>>>(stats, g3, be3, invN);
    bn_apply<<<applyGrid, 256, 0, stream>>>((const float4*)agg, dinv, b3, stats, a3,
                                            (float4*)d_out, N);
}

// Round 2
// 778.670 us; speedup vs baseline: 5.5573x; 5.5573x over previous
//
#include <hip/hip_runtime.h>

// GCN: 3 x (GCNConv -> BN(train) -> PReLU), N=100000, E=1600000, 128->64->64->64
// R2: replace atomic scatter (1.6GB writeback/layer) with CSR gather:
//  - build dst-sorted CSR once (histogram + scan + cursor fill)
//  - aggregate: 1 wave/node, 4 edges x 16 float4-lanes, shfl_xor reduce,
//    fused y = dinv*acc + b and BN stats accumulation
//  - gemm writes hs only; bn_apply is in-place elementwise

constexpr float BN_EPS = 1e-5f;

__global__ void count_deg_int(const int* __restrict__ dst, int* __restrict__ degi, int E) {
    int e = blockIdx.x * blockDim.x + threadIdx.x;
    if (e < E) atomicAdd(&degi[dst[e]], 1);
}

__global__ void finalize_dinv(const int* __restrict__ degi, float* __restrict__ dinv, int N) {
    int i = blockIdx.x * blockDim.x + threadIdx.x;
    if (i < N) dinv[i] = rsqrtf((float)degi[i] + 1.0f);  // +1 self-loop
}

// inclusive scan of degi within 256-blocks -> rowend; block totals -> blocksum
__global__ __launch_bounds__(256) void scan1(const int* __restrict__ degi,
                                             int* __restrict__ rowend,
                                             int* __restrict__ blocksum, int N) {
    __shared__ int tmp[256];
    int t = threadIdx.x;
    int i = blockIdx.x * 256 + t;
    int v = (i < N) ? degi[i] : 0;
    tmp[t] = v;
    __syncthreads();
    for (int off = 1; off < 256; off <<= 1) {
        int u = (t >= off) ? tmp[t - off] : 0;
        __syncthreads();
        tmp[t] += u;
        __syncthreads();
    }
    if (i < N) rowend[i] = tmp[t];
    if (t == 255) blocksum[blockIdx.x] = tmp[255];
}

// exclusive scan of blocksum in one 512-thread block
__global__ __launch_bounds__(512) void scan2(int* __restrict__ blocksum, int nb) {
    __shared__ int tmp[512];
    int t = threadIdx.x;
    int v = (t < nb) ? blocksum[t] : 0;
    tmp[t] = v;
    __syncthreads();
    for (int off = 1; off < 512; off <<= 1) {
        int u = (t >= off) ? tmp[t - off] : 0;
        __syncthreads();
        tmp[t] += u;
        __syncthreads();
    }
    if (t < nb) blocksum[t] = tmp[t] - v;  // exclusive
}

__global__ __launch_bounds__(256) void scan3(int* __restrict__ rowend,
                                             const int* __restrict__ blocksum, int N) {
    int i = blockIdx.x * 256 + threadIdx.x;
    if (i < N) rowend[i] += blocksum[blockIdx.x];
}

__global__ void init_cursor(const int* __restrict__ rowend, const int* __restrict__ degi,
                            int* __restrict__ cursor, int N) {
    int i = blockIdx.x * blockDim.x + threadIdx.x;
    if (i < N) cursor[i] = rowend[i] - degi[i];
}

__global__ void fill_csr(const int* __restrict__ src, const int* __restrict__ dst,
                         int* __restrict__ cursor, int* __restrict__ col, int E) {
    int e = blockIdx.x * blockDim.x + threadIdx.x;
    if (e < E) {
        int pos = atomicAdd(&cursor[dst[e]], 1);
        col[pos] = src[e];
    }
}

// hs[row][c] = (X[row][:] @ W[:][c]) * dinv[row]
template <int K>
__global__ __launch_bounds__(256) void gemm_scale(
    const float* __restrict__ X, const float* __restrict__ W,
    const float* __restrict__ dinv, float* __restrict__ hs, int N) {
    static_assert(K % 64 == 0, "K must be multiple of 64");
    __shared__ float Ws[K * 64];
    __shared__ float Xs[64 * 65];

    const int t = threadIdx.x;
    const int rowBase = blockIdx.x * 64;

    for (int q = t; q < K * 16; q += 256)
        ((float4*)Ws)[q] = ((const float4*)W)[q];

    const int tx = t & 15;
    const int ty = t >> 4;

    float acc[4][4];
#pragma unroll
    for (int i = 0; i < 4; ++i)
#pragma unroll
        for (int j = 0; j < 4; ++j) acc[i][j] = 0.f;

#pragma unroll
    for (int kh = 0; kh < K / 64; ++kh) {
        __syncthreads();
#pragma unroll
        for (int j = 0; j < 4; ++j) {
            int q = t + j * 256;
            int r = q >> 4, kk = q & 15;
            int row = rowBase + r;
            float4 v = make_float4(0.f, 0.f, 0.f, 0.f);
            if (row < N)
                v = *(const float4*)(X + (size_t)row * K + kh * 64 + kk * 4);
            float* p = &Xs[r * 65 + kk * 4];
            p[0] = v.x; p[1] = v.y; p[2] = v.z; p[3] = v.w;
        }
        __syncthreads();
#pragma unroll 8
        for (int k = 0; k < 64; ++k) {
            float4 w4 = *(const float4*)&Ws[(kh * 64 + k) * 64 + tx * 4];
#pragma unroll
            for (int i = 0; i < 4; ++i) {
                float xv = Xs[(ty * 4 + i) * 65 + k];
                acc[i][0] = fmaf(xv, w4.x, acc[i][0]);
                acc[i][1] = fmaf(xv, w4.y, acc[i][1]);
                acc[i][2] = fmaf(xv, w4.z, acc[i][2]);
                acc[i][3] = fmaf(xv, w4.w, acc[i][3]);
            }
        }
    }

#pragma unroll
    for (int i = 0; i < 4; ++i) {
        int row = rowBase + ty * 4 + i;
        if (row < N) {
            float dv = dinv[row];
            float4 o = make_float4(acc[i][0] * dv, acc[i][1] * dv,
                                   acc[i][2] * dv, acc[i][3] * dv);
            *(float4*)(hs + (size_t)row * 64 + tx * 4) = o;
        }
    }
}

// One wave per node: y[n] = dinv[n]*(hs[n] + sum_{src->n} hs[src]) + b
// Fused per-feature BN stats (sum, sumsq) -> global atomics once per block.
__global__ __launch_bounds__(256) void aggregate_bn(
    const float4* __restrict__ hs4, const int* __restrict__ col,
    const int* __restrict__ rowend, const int* __restrict__ degi,
    const float* __restrict__ dinv, const float* __restrict__ b,
    float* __restrict__ stats, float4* __restrict__ y4, int N) {
    const int t = threadIdx.x;
    const int lane = t & 63;
    const int wid = t >> 6;      // wave in block (0..3)
    const int fl = lane & 15;    // float4 feature index
    const int eg = lane >> 4;    // edge subgroup (0..3)

    __shared__ float lsum[64], lsq[64];
    if (t < 64) { lsum[t] = 0.f; lsq[t] = 0.f; }
    __syncthreads();

    float4 ssum = make_float4(0.f, 0.f, 0.f, 0.f);
    float4 ssq  = make_float4(0.f, 0.f, 0.f, 0.f);
    const float4 b4 = ((const float4*)b)[fl];
    const int waveStride = gridDim.x * 4;

    for (int n = blockIdx.x * 4 + wid; n < N; n += waveStride) {
        int deg = degi[n];
        int start = rowend[n] - deg;
        float4 acc = make_float4(0.f, 0.f, 0.f, 0.f);
        for (int i = eg; i < deg; i += 4) {
            int s = col[start + i];
            float4 v = hs4[(size_t)s * 16 + fl];
            acc.x += v.x; acc.y += v.y; acc.z += v.z; acc.w += v.w;
        }
        // reduce the 4 edge subgroups (xor lanes 16, 32)
        acc.x += __shfl_xor(acc.x, 16); acc.y += __shfl_xor(acc.y, 16);
        acc.z += __shfl_xor(acc.z, 16); acc.w += __shfl_xor(acc.w, 16);
        acc.x += __shfl_xor(acc.x, 32); acc.y += __shfl_xor(acc.y, 32);
        acc.z += __shfl_xor(acc.z, 32); acc.w += __shfl_xor(acc.w, 32);
        if (eg == 0) {
            float4 self = hs4[(size_t)n * 16 + fl];
            float dv = dinv[n];
            float4 yv;
            yv.x = fmaf(dv, acc.x + self.x, b4.x);
            yv.y = fmaf(dv, acc.y + self.y, b4.y);
            yv.z = fmaf(dv, acc.z + self.z, b4.z);
            yv.w = fmaf(dv, acc.w + self.w, b4.w);
            y4[(size_t)n * 16 + fl] = yv;
            ssum.x += yv.x; ssum.y += yv.y; ssum.z += yv.z; ssum.w += yv.w;
            ssq.x = fmaf(yv.x, yv.x, ssq.x); ssq.y = fmaf(yv.y, yv.y, ssq.y);
            ssq.z = fmaf(yv.z, yv.z, ssq.z); ssq.w = fmaf(yv.w, yv.w, ssq.w);
        }
    }
    if (eg == 0) {
        atomicAdd(&lsum[fl * 4 + 0], ssum.x); atomicAdd(&lsum[fl * 4 + 1], ssum.y);
        atomicAdd(&lsum[fl * 4 + 2], ssum.z); atomicAdd(&lsum[fl * 4 + 3], ssum.w);
        atomicAdd(&lsq[fl * 4 + 0], ssq.x);  atomicAdd(&lsq[fl * 4 + 1], ssq.y);
        atomicAdd(&lsq[fl * 4 + 2], ssq.z);  atomicAdd(&lsq[fl * 4 + 3], ssq.w);
    }
    __syncthreads();
    if (t < 64) atomicAdd(&stats[t], lsum[t]);
    else if (t < 128) atomicAdd(&stats[t], lsq[t - 64]);
}

__global__ void bn_final(float* __restrict__ stats, const float* __restrict__ g,
                         const float* __restrict__ be, float invN) {
    int c = threadIdx.x;  // 64 threads
    float mu = stats[c] * invN;
    float var = stats[64 + c] * invN - mu * mu;
    float sc = g[c] * rsqrtf(var + BN_EPS);
    stats[128 + c] = sc;
    stats[192 + c] = be[c] - mu * sc;
}

// z = prelu(y*scale + shift)  (elementwise; in-place safe)
__global__ __launch_bounds__(256) void bn_apply(
    const float4* __restrict__ y4, const float* __restrict__ stats,
    const float* __restrict__ a, float4* __restrict__ out4, int total4) {
    int i = blockIdx.x * blockDim.x + threadIdx.x;
    if (i >= total4) return;
    int cg = (i & 15) * 4;
    float4 v = y4[i];
    float4 o;
    {
        float z = fmaf(v.x, stats[128 + cg + 0], stats[192 + cg + 0]);
        o.x = z >= 0.f ? z : a[cg + 0] * z;
    }
    {
        float z = fmaf(v.y, stats[128 + cg + 1], stats[192 + cg + 1]);
        o.y = z >= 0.f ? z : a[cg + 1] * z;
    }
    {
        float z = fmaf(v.z, stats[128 + cg + 2], stats[192 + cg + 2]);
        o.z = z >= 0.f ? z : a[cg + 2] * z;
    }
    {
        float z = fmaf(v.w, stats[128 + cg + 3], stats[192 + cg + 3]);
        o.w = z >= 0.f ? z : a[cg + 3] * z;
    }
    out4[i] = o;
}

extern "C" void kernel_launch(void* const* d_in, const int* in_sizes, int n_in,
                              void* d_out, int out_size, void* d_ws, size_t ws_size,
                              hipStream_t stream) {
    const float* x  = (const float*)d_in[0];
    const int*   ei = (const int*)d_in[1];
    const int N = in_sizes[0] / 128;
    const int E = in_sizes[1] / 2;
    const int* srcp = ei;
    const int* dstp = ei + E;

    const float* W1 = (const float*)d_in[2];
    const float* b1 = (const float*)d_in[3];
    const float* g1 = (const float*)d_in[4];
    const float* be1 = (const float*)d_in[5];
    const float* a1 = (const float*)d_in[6];
    const float* W2 = (const float*)d_in[7];
    const float* b2 = (const float*)d_in[8];
    const float* g2 = (const float*)d_in[9];
    const float* be2 = (const float*)d_in[10];
    const float* a2 = (const float*)d_in[11];
    const float* W3 = (const float*)d_in[12];
    const float* b3 = (const float*)d_in[13];
    const float* g3 = (const float*)d_in[14];
    const float* be3 = (const float*)d_in[15];
    const float* a3 = (const float*)d_in[16];

    // ws layout (4B units):
    // dinv[N] f | degi[N] i | rowend[N] i | cursor[N] i | col[E] i |
    // blocksum[512] i | stats[256] f | hs[N*64] f | ybuf[N*64] f
    float* ws = (float*)d_ws;
    float* dinv   = ws;
    int*   degi   = (int*)(ws + N);
    int*   rowend = (int*)(ws + 2 * (size_t)N);
    int*   cursor = (int*)(ws + 3 * (size_t)N);
    int*   col    = (int*)(ws + 4 * (size_t)N);
    int*   blocksum = (int*)(ws + 4 * (size_t)N + E);
    float* stats  = ws + 4 * (size_t)N + E + 512;
    float* hs     = stats + 256;
    float* ybuf   = hs + (size_t)N * 64;

    const int nb1 = (N + 255) / 256;  // scan blocks (<=512 required)

    hipMemsetAsync(degi, 0, (size_t)N * sizeof(int), stream);
    count_deg_int<<<(E + 255) / 256, 256, 0, stream>>>(dstp, degi, E);
    finalize_dinv<<<nb1, 256, 0, stream>>>(degi, dinv, N);
    scan1<<<nb1, 256, 0, stream>>>(degi, rowend, blocksum, N);
    scan2<<<1, 512, 0, stream>>>(blocksum, nb1);
    scan3<<<nb1, 256, 0, stream>>>(rowend, blocksum, N);
    init_cursor<<<nb1, 256, 0, stream>>>(rowend, degi, cursor, N);
    fill_csr<<<(E + 255) / 256, 256, 0, stream>>>(srcp, dstp, cursor, col, E);

    const int gemmGrid = (N + 63) / 64;
    const int aggGrid = 2048;
    const int applyGrid = (N * 16 + 255) / 256;
    const float invN = 1.0f / (float)N;

    // ---- layer 1 (K=128) ----
    gemm_scale<128><<<gemmGrid, 256, 0, stream>>>(x, W1, dinv, hs, N);
    hipMemsetAsync(stats, 0, 128 * sizeof(float), stream);
    aggregate_bn<<<aggGrid, 256, 0, stream>>>((const float4*)hs, col, rowend, degi,
                                              dinv, b1, stats, (float4*)ybuf, N);
    bn_final<<<1, 64, 0, stream>>>(stats, g1, be1, invN);
    bn_apply<<<applyGrid, 256, 0, stream>>>((const float4*)ybuf, stats, a1,
                                            (float4*)ybuf, N * 16);

    // ---- layer 2 (K=64) ----
    gemm_scale<64><<<gemmGrid, 256, 0, stream>>>(ybuf, W2, dinv, hs, N);
    hipMemsetAsync(stats, 0, 128 * sizeof(float), stream);
    aggregate_bn<<<aggGrid, 256, 0, stream>>>((const float4*)hs, col, rowend, degi,
                                              dinv, b2, stats, (float4*)ybuf, N);
    bn_final<<<1, 64, 0, stream>>>(stats, g2, be2, invN);
    bn_apply<<<applyGrid, 256, 0, stream>>>((const float4*)ybuf, stats, a2,
                                            (float4*)ybuf, N * 16);

    // ---- layer 3 (K=64) ----
    gemm_scale<64><<<gemmGrid, 256, 0, stream>>>(ybuf, W3, dinv, hs, N);
    hipMemsetAsync(stats, 0, 128 * sizeof(float), stream);
    aggregate_bn<<<aggGrid, 256, 0, stream>>>((const float4*)hs, col, rowend, degi,
                                              dinv, b3, stats, (float4*)ybuf, N);
    bn_final<<<1, 64, 0, stream>>>(stats, g3, be3, invN);
    bn_apply<<<applyGrid, 256, 0, stream>>>((const float4*)ybuf, stats, a3,
                                            (float4*)d_out, N * 16);
}